// Round 7
// baseline (666.202 us; speedup 1.0000x reference)
//
#include <hip/hip_runtime.h>

#define D 64
#define NPB 128              // nodes per bucket (dstLocal: 7 bits)
#define NPB_SHIFT 7
#define MAXB 1024            // bound on bucket count B = ceil(N/NPB)
#define SCATTER_BLOCKS 512
#define SCATTER_T 512
#define HIST_BLOCKS 512
#define HIST_T 256

// round-to-nearest-even fp32 -> bf16
__device__ inline unsigned f2bf(float f) {
    unsigned u = __float_as_uint(f);
    return (u + 0x7FFFu + ((u >> 16) & 1u)) >> 16;
}

// ---------------------------------------------------------------------------
// zero helpers (ws is poisoned 0xAA every launch)
// ---------------------------------------------------------------------------
__global__ void zero_i_kernel(int* __restrict__ p, int n) {
    int i = blockIdx.x * blockDim.x + threadIdx.x;
    if (i < n) p[i] = 0;
}
__global__ void zero_f4_kernel(float4* __restrict__ p, int n4) {
    int i = blockIdx.x * blockDim.x + threadIdx.x;
    if (i < n4) p[i] = make_float4(0.f, 0.f, 0.f, 0.f);
}

// ---------------------------------------------------------------------------
// bucket histogram: LDS-staged, then one global atomic per (block,bucket)
// ---------------------------------------------------------------------------
__global__ __launch_bounds__(HIST_T) void hist_bucket_kernel(const int* __restrict__ dst,
                                                             int* __restrict__ cnt,
                                                             int E, int B) {
    __shared__ int lc[MAXB];
    for (int i = threadIdx.x; i < B; i += blockDim.x) lc[i] = 0;
    __syncthreads();
    int chunk = (E + gridDim.x - 1) / gridDim.x;
    int lo = blockIdx.x * chunk, hi = min(lo + chunk, E);
    for (int e = lo + threadIdx.x; e < hi; e += blockDim.x)
        atomicAdd(&lc[dst[e] >> NPB_SHIFT], 1);
    __syncthreads();
    for (int i = threadIdx.x; i < B; i += blockDim.x)
        if (lc[i]) atomicAdd(&cnt[i], lc[i]);
}

// ---------------------------------------------------------------------------
// exclusive scan of bucket counts (single block of MAXB threads)
// writes bucketStart[0..B] and cursor[0..B)
// ---------------------------------------------------------------------------
__global__ __launch_bounds__(MAXB) void scan_bucket_kernel(const int* __restrict__ cnt,
                                                           int* __restrict__ bucketStart,
                                                           int* __restrict__ cursor,
                                                           int B, int E) {
    __shared__ int sd[MAXB];
    int t = threadIdx.x;
    sd[t] = (t < B) ? cnt[t] : 0;
    __syncthreads();
    for (int st = 1; st < MAXB; st <<= 1) {
        int v = (t >= st) ? sd[t - st] : 0;
        __syncthreads();
        sd[t] += v;
        __syncthreads();
    }
    if (t < B) {
        int ex = (t == 0) ? 0 : sd[t - 1];
        bucketStart[t] = ex;
        cursor[t] = ex;
    }
    if (t == 0) bucketStart[B] = E;
}

// ---------------------------------------------------------------------------
// bucket scatter (two-pass per block): LDS chunk histogram -> reserve
// contiguous per-bucket ranges (1 global atomic per block x bucket) ->
// write. 512x512: 16 waves/CU (r6 ran 1 block/CU = 4 waves -> 6.6% occ,
// latency-starved at 46us). Runs ~3 entries so L2 still merges lines.
// Packing: x = src | dstLocal<<20, y = w bits.
// ---------------------------------------------------------------------------
__global__ __launch_bounds__(SCATTER_T) void bucket_scatter_kernel(
        const int* __restrict__ src, const int* __restrict__ dst,
        const float* __restrict__ w, int* __restrict__ cursor,
        int2* __restrict__ adjB, int E, int B) {
    __shared__ int lc[MAXB];
    __shared__ int lbase[MAXB];
    __shared__ int lfill[MAXB];
    int chunk = (E + gridDim.x - 1) / gridDim.x;
    int lo = blockIdx.x * chunk, hi = min(lo + chunk, E);
    for (int i = threadIdx.x; i < B; i += blockDim.x) { lc[i] = 0; lfill[i] = 0; }
    __syncthreads();
    for (int e = lo + threadIdx.x; e < hi; e += blockDim.x)
        atomicAdd(&lc[dst[e] >> NPB_SHIFT], 1);
    __syncthreads();
    for (int i = threadIdx.x; i < B; i += blockDim.x)
        lbase[i] = lc[i] ? atomicAdd(&cursor[i], lc[i]) : 0;
    __syncthreads();
    for (int e = lo + threadIdx.x; e < hi; e += blockDim.x) {
        int t = dst[e];
        int b = t >> NPB_SHIFT;
        int pos = lbase[b] + atomicAdd(&lfill[b], 1);
        adjB[pos] = make_int2(src[e] | ((t & (NPB - 1)) << 20), __float_as_int(w[e]));
    }
}

// ---------------------------------------------------------------------------
// Tiled row GEMM -> bf16 packed proj. Block = 64 rows; A transposed in LDS;
// theta in LDS; thread computes 4x4 block. __launch_bounds__(256,4) caps
// VGPR at 128 (r5: epilogue hoisting -> 252 VGPR, 9% occupancy).
// ---------------------------------------------------------------------------
__global__ __launch_bounds__(256, 4) void rowgemm_bf16_kernel(const float* __restrict__ A,
                                                              const float* __restrict__ theta,
                                                              unsigned short* __restrict__ proj16,
                                                              int N) {
    __shared__ float th[D * D];
    __shared__ float at[D][68];
    int t = threadIdx.x;
    int rowBase = blockIdx.x * 64;

#pragma unroll
    for (int i = 0; i < 4; ++i) {
        int f = t + i * 256;
        ((float4*)th)[f] = ((const float4*)theta)[f];
    }
#pragma unroll
    for (int i = 0; i < 4; ++i) {
        int f = t + i * 256;
        int row = f >> 4;
        int kv = f & 15;
        float4 v = make_float4(0.f, 0.f, 0.f, 0.f);
        if (rowBase + row < N) v = *(const float4*)&A[(size_t)(rowBase + row) * D + kv * 4];
        at[kv * 4 + 0][row] = v.x;
        at[kv * 4 + 1][row] = v.y;
        at[kv * 4 + 2][row] = v.z;
        at[kv * 4 + 3][row] = v.w;
    }
    __syncthreads();

    int c0 = (t & 15) * 4;
    int r0 = (t >> 4) * 4;
    float4 acc0 = make_float4(0.f, 0.f, 0.f, 0.f);
    float4 acc1 = acc0, acc2 = acc0, acc3 = acc0;

#pragma unroll 16
    for (int k = 0; k < D; ++k) {
        float4 bv = *(const float4*)&th[k * D + c0];
        float4 av = *(const float4*)&at[k][r0];
        acc0.x += av.x * bv.x; acc0.y += av.x * bv.y; acc0.z += av.x * bv.z; acc0.w += av.x * bv.w;
        acc1.x += av.y * bv.x; acc1.y += av.y * bv.y; acc1.z += av.y * bv.z; acc1.w += av.y * bv.w;
        acc2.x += av.z * bv.x; acc2.y += av.z * bv.y; acc2.z += av.z * bv.z; acc2.w += av.z * bv.w;
        acc3.x += av.w * bv.x; acc3.y += av.w * bv.y; acc3.z += av.w * bv.z; acc3.w += av.w * bv.w;
    }

    float4 accs[4] = {acc0, acc1, acc2, acc3};
#pragma unroll
    for (int i = 0; i < 4; ++i) {
        int r = rowBase + r0 + i;
        if (r < N) {
            unsigned lo = f2bf(accs[i].x) | (f2bf(accs[i].y) << 16);
            unsigned hi = f2bf(accs[i].z) | (f2bf(accs[i].w) << 16);
            *(uint2*)&proj16[(size_t)r * D + c0] = make_uint2(lo, hi);
        }
    }
}

// ---------------------------------------------------------------------------
// bucket gather v2: one block per bucket, consumes bucket-grouped adjB
// directly (no node-level sort needed). 128x64 fp32 LDS tile (32 KB ->
// 4 blocks/CU by wave cap). Each HALF-WAVE owns one edge per iteration:
// uniform 8B entry load + coalesced 128B bf16 row load + 2 ds_add_f32
// (lane k -> dword dL*64+2k: even banks 2-way = free; +1 -> odd banks).
// Iterations are independent & unrolled x2 so entry/row loads pipeline
// (r4's failure was one batched entry load feeding 64 serial row loads).
// ---------------------------------------------------------------------------
__global__ __launch_bounds__(512) void bucket_gather_kernel(
        const int* __restrict__ bucketStart, const int2* __restrict__ adjB,
        const unsigned* __restrict__ projU, float* __restrict__ out, int N) {
    __shared__ float tile[NPB * D];          // 32 KB
    int t = threadIdx.x;
    float4* t4 = (float4*)tile;
#pragma unroll
    for (int q = 0; q < (NPB * D / 4) / 512; ++q)    // 4
        t4[t + q * 512] = make_float4(0.f, 0.f, 0.f, 0.f);
    __syncthreads();

    int b = blockIdx.x;
    int beg = bucketStart[b], end = bucketStart[b + 1];
    int k = t & 31;                // word within the 32-word bf16 row
    int halfId = t >> 5;           // 0..15
    const int NH = 512 / 32;       // 16 half-waves per block

    int i = beg + halfId;
    for (; i + NH < end; i += 2 * NH) {
        int2 a0 = adjB[i];
        int2 a1 = adjB[i + NH];
        unsigned p0 = projU[(size_t)(a0.x & 0xFFFFF) * 32 + k];
        unsigned p1 = projU[(size_t)(a1.x & 0xFFFFF) * 32 + k];
        float w0 = __int_as_float(a0.y);
        float w1 = __int_as_float(a1.y);
        int d0 = ((unsigned)a0.x) >> 20;
        int d1 = ((unsigned)a1.x) >> 20;
        atomicAdd(&tile[d0 * D + 2 * k],     w0 * __uint_as_float(p0 << 16));
        atomicAdd(&tile[d0 * D + 2 * k + 1], w0 * __uint_as_float(p0 & 0xFFFF0000u));
        atomicAdd(&tile[d1 * D + 2 * k],     w1 * __uint_as_float(p1 << 16));
        atomicAdd(&tile[d1 * D + 2 * k + 1], w1 * __uint_as_float(p1 & 0xFFFF0000u));
    }
    for (; i < end; i += NH) {
        int2 a0 = adjB[i];
        unsigned p0 = projU[(size_t)(a0.x & 0xFFFFF) * 32 + k];
        float w0 = __int_as_float(a0.y);
        int d0 = ((unsigned)a0.x) >> 20;
        atomicAdd(&tile[d0 * D + 2 * k],     w0 * __uint_as_float(p0 << 16));
        atomicAdd(&tile[d0 * D + 2 * k + 1], w0 * __uint_as_float(p0 & 0xFFFF0000u));
    }
    __syncthreads();

    int nodeBase = b * NPB;
#pragma unroll
    for (int q = 0; q < (NPB * (D / 4)) / 512; ++q) {  // 4
        int f = t + q * 512;
        int row = f >> 4;
        int node = nodeBase + row;
        if (node < N)
            *(float4*)&out[(size_t)node * D + (f & 15) * 4] = t4[f];
    }
}

// ---------------------------------------------------------------------------
// fallback path (atomic scatter + fp32 row GEMM) if ws/shape checks fail
// ---------------------------------------------------------------------------
__global__ void scatter_kernel(const int* __restrict__ src, const int* __restrict__ dst,
                               const float* __restrict__ w, const float* __restrict__ data,
                               float* __restrict__ agg, int E) {
    int tid = blockIdx.x * blockDim.x + threadIdx.x;
    int e = tid >> 6;
    int d = tid & 63;
    if (e >= E) return;
    float val = w[e] * data[(size_t)src[e] * D + d];
    atomicAdd(&agg[(size_t)dst[e] * D + d], val);
}

__global__ __launch_bounds__(256, 4) void rowgemm_f32_kernel(const float* __restrict__ A,
                                                             const float* __restrict__ theta,
                                                             float* __restrict__ out, int N) {
    __shared__ float th[D * D];
    __shared__ float at[D][68];
    int t = threadIdx.x;
    int rowBase = blockIdx.x * 64;
#pragma unroll
    for (int i = 0; i < 4; ++i) {
        int f = t + i * 256;
        ((float4*)th)[f] = ((const float4*)theta)[f];
    }
#pragma unroll
    for (int i = 0; i < 4; ++i) {
        int f = t + i * 256;
        int row = f >> 4;
        int kv = f & 15;
        float4 v = make_float4(0.f, 0.f, 0.f, 0.f);
        if (rowBase + row < N) v = *(const float4*)&A[(size_t)(rowBase + row) * D + kv * 4];
        at[kv * 4 + 0][row] = v.x;
        at[kv * 4 + 1][row] = v.y;
        at[kv * 4 + 2][row] = v.z;
        at[kv * 4 + 3][row] = v.w;
    }
    __syncthreads();
    int c0 = (t & 15) * 4;
    int r0 = (t >> 4) * 4;
    float4 acc0 = make_float4(0.f, 0.f, 0.f, 0.f);
    float4 acc1 = acc0, acc2 = acc0, acc3 = acc0;
#pragma unroll 16
    for (int kk = 0; kk < D; ++kk) {
        float4 bv = *(const float4*)&th[kk * D + c0];
        float4 av = *(const float4*)&at[kk][r0];
        acc0.x += av.x * bv.x; acc0.y += av.x * bv.y; acc0.z += av.x * bv.z; acc0.w += av.x * bv.w;
        acc1.x += av.y * bv.x; acc1.y += av.y * bv.y; acc1.z += av.y * bv.z; acc1.w += av.y * bv.w;
        acc2.x += av.z * bv.x; acc2.y += av.z * bv.y; acc2.z += av.z * bv.z; acc2.w += av.z * bv.w;
        acc3.x += av.w * bv.x; acc3.y += av.w * bv.y; acc3.z += av.w * bv.z; acc3.w += av.w * bv.w;
    }
    float4 accs[4] = {acc0, acc1, acc2, acc3};
#pragma unroll
    for (int i = 0; i < 4; ++i) {
        int r = rowBase + r0 + i;
        if (r < N) *(float4*)&out[(size_t)r * D + c0] = accs[i];
    }
}

extern "C" void kernel_launch(void* const* d_in, const int* in_sizes, int n_in,
                              void* d_out, int out_size, void* d_ws, size_t ws_size,
                              hipStream_t stream) {
    const int*   src   = (const int*)d_in[0];
    const int*   dst   = (const int*)d_in[1];
    const float* w     = (const float*)d_in[2];
    const float* data  = (const float*)d_in[3];
    const float* theta = (const float*)d_in[4];
    const int E = in_sizes[0];
    const int N = in_sizes[3] / D;
    float* out = (float*)d_out;

    const int B = (N + NPB - 1) / NPB;

    // ws layout: proj16 (bf16) | adjB | cnt[B] | bucketStart[B+1] | cursor[B]
    size_t projBytes = (size_t)N * D * 2;
    size_t need = projBytes + (size_t)E * 8 + ((size_t)3 * B + 2) * 4 + 256;

    if (ws_size >= need && N < (1 << 20) && B <= MAXB) {
        unsigned short* proj16 = (unsigned short*)d_ws;
        int2* adjB        = (int2*)((char*)d_ws + projBytes);
        int*  cnt         = (int*)(adjB + E);
        int*  bucketStart = cnt + B;
        int*  cursor      = bucketStart + (B + 1);

        zero_i_kernel<<<(B + 255) / 256, 256, 0, stream>>>(cnt, B);
        hist_bucket_kernel<<<HIST_BLOCKS, HIST_T, 0, stream>>>(dst, cnt, E, B);
        scan_bucket_kernel<<<1, MAXB, 0, stream>>>(cnt, bucketStart, cursor, B, E);
        bucket_scatter_kernel<<<SCATTER_BLOCKS, SCATTER_T, 0, stream>>>(src, dst, w, cursor, adjB, E, B);
        rowgemm_bf16_kernel<<<(N + 63) / 64, 256, 0, stream>>>(data, theta, proj16, N);
        bucket_gather_kernel<<<B, 512, 0, stream>>>(bucketStart, adjB, (const unsigned*)proj16, out, N);
    } else {
        float* agg = (float*)d_ws;
        int n4 = (N * D) / 4;
        zero_f4_kernel<<<(n4 + 255) / 256, 256, 0, stream>>>((float4*)agg, n4);
        long long total = (long long)E * D;
        scatter_kernel<<<(int)((total + 255) / 256), 256, 0, stream>>>(src, dst, w, data, agg, E);
        rowgemm_f32_kernel<<<(N + 63) / 64, 256, 0, stream>>>(agg, theta, out, N);
    }
}

// Round 8
// 211.652 us; speedup vs baseline: 3.1476x; 3.1476x over previous
//
#include <hip/hip_runtime.h>

#define D 64
#define NPB 128              // nodes per bucket (dstLocal: 7 bits)
#define NPB_SHIFT 7
#define MAXB 1024            // bound on bucket count B = ceil(N/NPB)
#define SCATTER_BLOCKS 512
#define SCATTER_T 512
#define HIST_BLOCKS 512
#define HIST_T 256

// round-to-nearest-even fp32 -> bf16
__device__ inline unsigned f2bf(float f) {
    unsigned u = __float_as_uint(f);
    return (u + 0x7FFFu + ((u >> 16) & 1u)) >> 16;
}

// ---------------------------------------------------------------------------
// zero helpers (ws is poisoned 0xAA every launch)
// ---------------------------------------------------------------------------
__global__ void zero_i_kernel(int* __restrict__ p, int n) {
    int i = blockIdx.x * blockDim.x + threadIdx.x;
    if (i < n) p[i] = 0;
}
__global__ void zero_f4_kernel(float4* __restrict__ p, int n4) {
    int i = blockIdx.x * blockDim.x + threadIdx.x;
    if (i < n4) p[i] = make_float4(0.f, 0.f, 0.f, 0.f);
}

// ---------------------------------------------------------------------------
// bucket histogram: LDS-staged, then one global atomic per (block,bucket)
// ---------------------------------------------------------------------------
__global__ __launch_bounds__(HIST_T) void hist_bucket_kernel(const int* __restrict__ dst,
                                                             int* __restrict__ cnt,
                                                             int E, int B) {
    __shared__ int lc[MAXB];
    for (int i = threadIdx.x; i < B; i += blockDim.x) lc[i] = 0;
    __syncthreads();
    int chunk = (E + gridDim.x - 1) / gridDim.x;
    int lo = blockIdx.x * chunk, hi = min(lo + chunk, E);
    for (int e = lo + threadIdx.x; e < hi; e += blockDim.x)
        atomicAdd(&lc[dst[e] >> NPB_SHIFT], 1);
    __syncthreads();
    for (int i = threadIdx.x; i < B; i += blockDim.x)
        if (lc[i]) atomicAdd(&cnt[i], lc[i]);
}

// ---------------------------------------------------------------------------
// exclusive scan of bucket counts (single block of MAXB threads)
// writes bucketStart[0..B], cursor[0..B), rowStart[N] = E
// ---------------------------------------------------------------------------
__global__ __launch_bounds__(MAXB) void scan_bucket_kernel(const int* __restrict__ cnt,
                                                           int* __restrict__ bucketStart,
                                                           int* __restrict__ cursor,
                                                           int* __restrict__ rowStartN,
                                                           int B, int E) {
    __shared__ int sd[MAXB];
    int t = threadIdx.x;
    sd[t] = (t < B) ? cnt[t] : 0;
    __syncthreads();
    for (int st = 1; st < MAXB; st <<= 1) {
        int v = (t >= st) ? sd[t - st] : 0;
        __syncthreads();
        sd[t] += v;
        __syncthreads();
    }
    if (t < B) {
        int ex = (t == 0) ? 0 : sd[t - 1];
        bucketStart[t] = ex;
        cursor[t] = ex;
    }
    if (t == 0) { bucketStart[B] = E; *rowStartN = E; }
}

// ---------------------------------------------------------------------------
// bucket scatter (two-pass per block): LDS chunk histogram -> reserve
// contiguous per-bucket ranges (1 global atomic per block x bucket) ->
// write. 512x512 = 2 blocks/CU x 8 waves = 16 waves/CU (r6: 4 waves/CU,
// VALU 1.2%, latency-starved at 46us).
// Packing: x = src | dstLocal<<20, y = w bits.
// ---------------------------------------------------------------------------
__global__ __launch_bounds__(SCATTER_T) void bucket_scatter_kernel(
        const int* __restrict__ src, const int* __restrict__ dst,
        const float* __restrict__ w, int* __restrict__ cursor,
        int2* __restrict__ adjB, int E, int B) {
    __shared__ int lc[MAXB];
    __shared__ int lbase[MAXB];
    __shared__ int lfill[MAXB];
    int chunk = (E + gridDim.x - 1) / gridDim.x;
    int lo = blockIdx.x * chunk, hi = min(lo + chunk, E);
    for (int i = threadIdx.x; i < B; i += blockDim.x) { lc[i] = 0; lfill[i] = 0; }
    __syncthreads();
    for (int e = lo + threadIdx.x; e < hi; e += blockDim.x)
        atomicAdd(&lc[dst[e] >> NPB_SHIFT], 1);
    __syncthreads();
    for (int i = threadIdx.x; i < B; i += blockDim.x)
        lbase[i] = lc[i] ? atomicAdd(&cursor[i], lc[i]) : 0;
    __syncthreads();
    for (int e = lo + threadIdx.x; e < hi; e += blockDim.x) {
        int t = dst[e];
        int b = t >> NPB_SHIFT;
        int pos = lbase[b] + atomicAdd(&lfill[b], 1);
        adjB[pos] = make_int2(src[e] | ((t & (NPB - 1)) << 20), __float_as_int(w[e]));
    }
}

// ---------------------------------------------------------------------------
// per-bucket LDS counting sort: bucket-grouped adjB -> node-grouped adj
// (plain src in .x), and emit rowStart. Reads coalesced; writes scattered
// only within the bucket's ~12KB window (L2 absorbs).
// ---------------------------------------------------------------------------
__global__ __launch_bounds__(256) void sort_bucket_kernel(
        const int2* __restrict__ adjB, const int* __restrict__ bucketStart,
        int2* __restrict__ adj, int* __restrict__ rowStart, int N) {
    __shared__ int cnt[NPB];
    __shared__ int pre[NPB];
    __shared__ int fill[NPB];
    int b = blockIdx.x;
    int beg = bucketStart[b], end = bucketStart[b + 1];
    int t = threadIdx.x;
    if (t < NPB) { cnt[t] = 0; fill[t] = 0; }
    __syncthreads();
    for (int e = beg + t; e < end; e += blockDim.x)
        atomicAdd(&cnt[((unsigned)adjB[e].x) >> 20], 1);
    __syncthreads();
    if (t < NPB) pre[t] = cnt[t];
    __syncthreads();
    for (int st = 1; st < NPB; st <<= 1) {
        int v = (t < NPB && t >= st) ? pre[t - st] : 0;
        __syncthreads();
        if (t < NPB) pre[t] += v;
        __syncthreads();
    }
    if (t < NPB) {
        int node = b * NPB + t;
        if (node < N) rowStart[node] = beg + ((t == 0) ? 0 : pre[t - 1]);
    }
    __syncthreads();
    for (int e = beg + t; e < end; e += blockDim.x) {
        int2 a = adjB[e];
        int dL = ((unsigned)a.x) >> 20;
        int base = beg + ((dL == 0) ? 0 : pre[dL - 1]);
        int pos = base + atomicAdd(&fill[dL], 1);
        adj[pos] = make_int2(a.x & 0xFFFFF, a.y);
    }
}

// ---------------------------------------------------------------------------
// Tiled row GEMM -> bf16 packed proj. Block = 64 rows; A transposed in LDS;
// theta in LDS; thread computes 4x4 block. __launch_bounds__(256,4) caps
// VGPR at 128 (r5: epilogue hoisting -> 252 VGPR, 9% occupancy).
// ---------------------------------------------------------------------------
__global__ __launch_bounds__(256, 4) void rowgemm_bf16_kernel(const float* __restrict__ A,
                                                              const float* __restrict__ theta,
                                                              unsigned short* __restrict__ proj16,
                                                              int N) {
    __shared__ float th[D * D];
    __shared__ float at[D][68];
    int t = threadIdx.x;
    int rowBase = blockIdx.x * 64;

#pragma unroll
    for (int i = 0; i < 4; ++i) {
        int f = t + i * 256;
        ((float4*)th)[f] = ((const float4*)theta)[f];
    }
#pragma unroll
    for (int i = 0; i < 4; ++i) {
        int f = t + i * 256;
        int row = f >> 4;
        int kv = f & 15;
        float4 v = make_float4(0.f, 0.f, 0.f, 0.f);
        if (rowBase + row < N) v = *(const float4*)&A[(size_t)(rowBase + row) * D + kv * 4];
        at[kv * 4 + 0][row] = v.x;
        at[kv * 4 + 1][row] = v.y;
        at[kv * 4 + 2][row] = v.z;
        at[kv * 4 + 3][row] = v.w;
    }
    __syncthreads();

    int c0 = (t & 15) * 4;
    int r0 = (t >> 4) * 4;
    float4 acc0 = make_float4(0.f, 0.f, 0.f, 0.f);
    float4 acc1 = acc0, acc2 = acc0, acc3 = acc0;

#pragma unroll 16
    for (int k = 0; k < D; ++k) {
        float4 bv = *(const float4*)&th[k * D + c0];
        float4 av = *(const float4*)&at[k][r0];
        acc0.x += av.x * bv.x; acc0.y += av.x * bv.y; acc0.z += av.x * bv.z; acc0.w += av.x * bv.w;
        acc1.x += av.y * bv.x; acc1.y += av.y * bv.y; acc1.z += av.y * bv.z; acc1.w += av.y * bv.w;
        acc2.x += av.z * bv.x; acc2.y += av.z * bv.y; acc2.z += av.z * bv.z; acc2.w += av.z * bv.w;
        acc3.x += av.w * bv.x; acc3.y += av.w * bv.y; acc3.z += av.w * bv.z; acc3.w += av.w * bv.w;
    }

    float4 accs[4] = {acc0, acc1, acc2, acc3};
#pragma unroll
    for (int i = 0; i < 4; ++i) {
        int r = rowBase + r0 + i;
        if (r < N) {
            unsigned lo = f2bf(accs[i].x) | (f2bf(accs[i].y) << 16);
            unsigned hi = f2bf(accs[i].z) | (f2bf(accs[i].w) << 16);
            *(uint2*)&proj16[(size_t)r * D + c0] = make_uint2(lo, hi);
        }
    }
}

// ---------------------------------------------------------------------------
// gather v3: one wave per node on node-CSR. Each HALF-wave (32 lanes)
// handles 4 edges per iteration via direct uniform-address adj loads
// (HW broadcast, L1-hit -> no shfl/DS-pipe traffic). 4 independent 256B
// proj row loads in flight per wave (r7 post-mortem: MLP on proj rows is
// everything; LDS-tile variants serialize). Tail: predicated weight=0.
// ---------------------------------------------------------------------------
__global__ void gather_kernel(const int* __restrict__ rowStart, const int2* __restrict__ adj,
                              const unsigned* __restrict__ projU, float* __restrict__ out, int N) {
    int wid = (blockIdx.x * blockDim.x + threadIdx.x) >> 6;
    int lane = threadIdx.x & 63;
    if (wid >= N) return;
    int beg = rowStart[wid];
    int end = rowStart[wid + 1];
    int half = lane >> 5;
    int k = lane & 31;

    float2 acc0 = make_float2(0.f, 0.f);
    float2 acc1 = acc0, acc2 = acc0, acc3 = acc0;

    for (int it = beg; it < end; it += 8) {
        // edges it+0..it+7; half h takes it+2u+h for u=0..3
        int e0 = it + 0 + half;
        int e1 = it + 2 + half;
        int e2 = it + 4 + half;
        int e3 = it + 6 + half;
        int2 a0 = adj[e0 < end ? e0 : beg];
        int2 a1 = adj[e1 < end ? e1 : beg];
        int2 a2 = adj[e2 < end ? e2 : beg];
        int2 a3 = adj[e3 < end ? e3 : beg];
        float w0 = (e0 < end) ? __int_as_float(a0.y) : 0.f;
        float w1 = (e1 < end) ? __int_as_float(a1.y) : 0.f;
        float w2 = (e2 < end) ? __int_as_float(a2.y) : 0.f;
        float w3 = (e3 < end) ? __int_as_float(a3.y) : 0.f;
        unsigned p0 = projU[(size_t)a0.x * 32 + k];
        unsigned p1 = projU[(size_t)a1.x * 32 + k];
        unsigned p2 = projU[(size_t)a2.x * 32 + k];
        unsigned p3 = projU[(size_t)a3.x * 32 + k];
        acc0.x += w0 * __uint_as_float(p0 << 16);
        acc0.y += w0 * __uint_as_float(p0 & 0xFFFF0000u);
        acc1.x += w1 * __uint_as_float(p1 << 16);
        acc1.y += w1 * __uint_as_float(p1 & 0xFFFF0000u);
        acc2.x += w2 * __uint_as_float(p2 << 16);
        acc2.y += w2 * __uint_as_float(p2 & 0xFFFF0000u);
        acc3.x += w3 * __uint_as_float(p3 << 16);
        acc3.y += w3 * __uint_as_float(p3 & 0xFFFF0000u);
    }
    float2 acc = make_float2(acc0.x + acc1.x + acc2.x + acc3.x,
                             acc0.y + acc1.y + acc2.y + acc3.y);
    acc.x += __shfl(acc.x, lane ^ 32, 64);
    acc.y += __shfl(acc.y, lane ^ 32, 64);
    if (half == 0)
        *(float2*)&out[(size_t)wid * D + 2 * k] = acc;   // 32 lanes x 8B coalesced
}

// ---------------------------------------------------------------------------
// fallback path (atomic scatter + fp32 row GEMM) if ws/shape checks fail
// ---------------------------------------------------------------------------
__global__ void scatter_kernel(const int* __restrict__ src, const int* __restrict__ dst,
                               const float* __restrict__ w, const float* __restrict__ data,
                               float* __restrict__ agg, int E) {
    int tid = blockIdx.x * blockDim.x + threadIdx.x;
    int e = tid >> 6;
    int d = tid & 63;
    if (e >= E) return;
    float val = w[e] * data[(size_t)src[e] * D + d];
    atomicAdd(&agg[(size_t)dst[e] * D + d], val);
}

__global__ __launch_bounds__(256, 4) void rowgemm_f32_kernel(const float* __restrict__ A,
                                                             const float* __restrict__ theta,
                                                             float* __restrict__ out, int N) {
    __shared__ float th[D * D];
    __shared__ float at[D][68];
    int t = threadIdx.x;
    int rowBase = blockIdx.x * 64;
#pragma unroll
    for (int i = 0; i < 4; ++i) {
        int f = t + i * 256;
        ((float4*)th)[f] = ((const float4*)theta)[f];
    }
#pragma unroll
    for (int i = 0; i < 4; ++i) {
        int f = t + i * 256;
        int row = f >> 4;
        int kv = f & 15;
        float4 v = make_float4(0.f, 0.f, 0.f, 0.f);
        if (rowBase + row < N) v = *(const float4*)&A[(size_t)(rowBase + row) * D + kv * 4];
        at[kv * 4 + 0][row] = v.x;
        at[kv * 4 + 1][row] = v.y;
        at[kv * 4 + 2][row] = v.z;
        at[kv * 4 + 3][row] = v.w;
    }
    __syncthreads();
    int c0 = (t & 15) * 4;
    int r0 = (t >> 4) * 4;
    float4 acc0 = make_float4(0.f, 0.f, 0.f, 0.f);
    float4 acc1 = acc0, acc2 = acc0, acc3 = acc0;
#pragma unroll 16
    for (int kk = 0; kk < D; ++kk) {
        float4 bv = *(const float4*)&th[kk * D + c0];
        float4 av = *(const float4*)&at[kk][r0];
        acc0.x += av.x * bv.x; acc0.y += av.x * bv.y; acc0.z += av.x * bv.z; acc0.w += av.x * bv.w;
        acc1.x += av.y * bv.x; acc1.y += av.y * bv.y; acc1.z += av.y * bv.z; acc1.w += av.y * bv.w;
        acc2.x += av.z * bv.x; acc2.y += av.z * bv.y; acc2.z += av.z * bv.z; acc2.w += av.z * bv.w;
        acc3.x += av.w * bv.x; acc3.y += av.w * bv.y; acc3.z += av.w * bv.z; acc3.w += av.w * bv.w;
    }
    float4 accs[4] = {acc0, acc1, acc2, acc3};
#pragma unroll
    for (int i = 0; i < 4; ++i) {
        int r = rowBase + r0 + i;
        if (r < N) *(float4*)&out[(size_t)r * D + c0] = accs[i];
    }
}

extern "C" void kernel_launch(void* const* d_in, const int* in_sizes, int n_in,
                              void* d_out, int out_size, void* d_ws, size_t ws_size,
                              hipStream_t stream) {
    const int*   src   = (const int*)d_in[0];
    const int*   dst   = (const int*)d_in[1];
    const float* w     = (const float*)d_in[2];
    const float* data  = (const float*)d_in[3];
    const float* theta = (const float*)d_in[4];
    const int E = in_sizes[0];
    const int N = in_sizes[3] / D;
    float* out = (float*)d_out;

    const int B = (N + NPB - 1) / NPB;

    // ws layout: proj16 (bf16) | adjB | adj | cnt[B] | bucketStart[B+1] |
    //            cursor[B] | rowStart[N+1]
    size_t projBytes = (size_t)N * D * 2;
    size_t need = projBytes + (size_t)E * 8 * 2
                + ((size_t)3 * B + 2) * 4 + ((size_t)N + 1) * 4 + 256;

    if (ws_size >= need && N < (1 << 20) && B <= MAXB) {
        unsigned short* proj16 = (unsigned short*)d_ws;
        int2* adjB        = (int2*)((char*)d_ws + projBytes);
        int2* adj         = adjB + E;
        int*  cnt         = (int*)(adj + E);
        int*  bucketStart = cnt + B;
        int*  cursor      = bucketStart + (B + 1);
        int*  rowStart    = cursor + B;

        zero_i_kernel<<<(B + 255) / 256, 256, 0, stream>>>(cnt, B);
        hist_bucket_kernel<<<HIST_BLOCKS, HIST_T, 0, stream>>>(dst, cnt, E, B);
        scan_bucket_kernel<<<1, MAXB, 0, stream>>>(cnt, bucketStart, cursor, rowStart + N, B, E);
        bucket_scatter_kernel<<<SCATTER_BLOCKS, SCATTER_T, 0, stream>>>(src, dst, w, cursor, adjB, E, B);
        sort_bucket_kernel<<<B, 256, 0, stream>>>(adjB, bucketStart, adj, rowStart, N);
        rowgemm_bf16_kernel<<<(N + 63) / 64, 256, 0, stream>>>(data, theta, proj16, N);
        gather_kernel<<<(N + 3) / 4, 256, 0, stream>>>(rowStart, adj, (const unsigned*)proj16, out, N);
    } else {
        float* agg = (float*)d_ws;
        int n4 = (N * D) / 4;
        zero_f4_kernel<<<(n4 + 255) / 256, 256, 0, stream>>>((float4*)agg, n4);
        long long total = (long long)E * D;
        scatter_kernel<<<(int)((total + 255) / 256), 256, 0, stream>>>(src, dst, w, data, agg, E);
        rowgemm_f32_kernel<<<(N + 63) / 64, 256, 0, stream>>>(agg, theta, out, N);
    }
}